// Round 4
// baseline (17339.577 us; speedup 1.0000x reference)
//
#include <hip/hip_runtime.h>
#include <hip/hip_bf16.h>
#include <stdint.h>

// Problem constants (from reference)
#define VOCAB 400000
#define EMB_D 50
#define RNN   512
#define HID   1024
#define SEQ   8192

// Canary marking "H slot not yet written". tanh output is in (-1,1) and h0=0,
// so a stored value can never equal 2.0f. Data word doubles as readiness flag.
#define CANARY_BITS 0x40000000u   // 2.0f
#define MAGIC       0x5a5a5a5au

// Poll cap: converts a pathological failure into a wrong answer, not a hang.
#define SPIN_CAP 65536

// ctl layout (ints). REGION A (agent-scope atomics ONLY, MALL-resident):
//   [0..7]  per-XCD arrival counters
//   [8]     elected XCD id (-1)
//   [9]     vcount  (verdicts posted)
//   [10]    vand    (AND of verdicts, init 1)
// REGION B (sc0 ops ONLY, elected-XCD-L2-resident), 256B away so the two
// coherence domains NEVER share a cache line (round-3 bug: sc0-dirty L2 line
// write-back clobbered MALL-side atomic words sharing the line):
//   [64..71] sc0 validation tokens
#define CTL_INTS 128

// ---------------------------------------------------------------------------
// sc0 memory ops: bypass L1, served by the (per-XCD, CU-shared) L2.
// Coherent ONLY among CUs on the same XCD -- workers are guaranteed same-XCD
// by the election below, and the assumption is runtime-validated.
// ---------------------------------------------------------------------------
__device__ __forceinline__ unsigned load_u32_sc0(const unsigned* p) {
    unsigned v;
    asm volatile("global_load_dword %0, %1, off sc0\n\ts_waitcnt vmcnt(0)"
                 : "=v"(v) : "v"(p) : "memory");
    return v;
}
__device__ __forceinline__ void store_u32_sc0(unsigned* p, unsigned v) {
    asm volatile("global_store_dword %0, %1, off sc0" :: "v"(p), "v"(v) : "memory");
}

// ---------------------------------------------------------------------------
// K_detect: decide whether token buffers are int32 or int64 (high dwords 0).
// ---------------------------------------------------------------------------
__global__ void k_detect(const unsigned int* s1, const unsigned int* s2,
                         unsigned int* flag) {
    __shared__ unsigned int red[256];
    unsigned int x = 0;
    for (int i = threadIdx.x; i < SEQ / 2; i += 256) {
        x |= s1[2 * i + 1];
        x |= s2[2 * i + 1];
    }
    red[threadIdx.x] = x;
    __syncthreads();
    for (int s = 128; s > 0; s >>= 1) {
        if (threadIdx.x < s) red[threadIdx.x] |= red[threadIdx.x + s];
        __syncthreads();
    }
    if (threadIdx.x == 0) *flag = (red[0] != 0) ? 1u : 0u;
}

// ---------------------------------------------------------------------------
// K_init: H[0][:] = 0, H[1..SEQ][:] = canary, ctl init.
// ---------------------------------------------------------------------------
__global__ void k_init(float* HA, float* HB, int* ctl) {
    if (blockIdx.x == 0 && threadIdx.x < CTL_INTS) {
        int i = threadIdx.x;
        int v = 0;
        if (i == 8) v = -1;        // elected
        if (i == 10) v = 1;        // vand
        ctl[i] = v;
    }
    const size_t n = (size_t)(SEQ + 1) * RNN;
    const float canary = __uint_as_float(CANARY_BITS);
    size_t i = (size_t)blockIdx.x * blockDim.x + threadIdx.x;
    const size_t stride = (size_t)gridDim.x * blockDim.x;
    for (; i < n; i += stride) {
        float v = (i < RNN) ? 0.0f : canary;
        HA[i] = v;
        HB[i] = v;
    }
}

// ---------------------------------------------------------------------------
// K_xp: fused embedding gather + input projection.
// ---------------------------------------------------------------------------
__global__ __launch_bounds__(512) void k_xp(const void* s_tok,
                                            const float* __restrict__ emb,
                                            const float* __restrict__ Wih,
                                            float* __restrict__ XP,
                                            const unsigned int* __restrict__ flag) {
    const int tb = blockIdx.x;
    const int r  = threadIdx.x;
    const bool i32 = (*flag != 0);

    float wih[EMB_D];
#pragma unroll
    for (int k = 0; k < EMB_D; ++k) wih[k] = Wih[r * EMB_D + k];

    __shared__ float e[64];

    for (int tt = 0; tt < 64; ++tt) {
        const int t = tb * 64 + tt;
        long long tok;
        if (i32) tok = (long long)((const int*)s_tok)[t];
        else     tok = ((const long long*)s_tok)[t];
        if (r < EMB_D) e[r] = emb[(size_t)tok * EMB_D + r];
        __syncthreads();
        float acc = 0.0f;
#pragma unroll
        for (int k = 0; k < EMB_D; ++k) acc = fmaf(wih[k], e[k], acc);
        XP[(size_t)t * RNN + r] = acc;
        __syncthreads();
    }
}

// ---------------------------------------------------------------------------
// rnn_rec: serial recurrence, both sequences interleaved, 8 worker WGs
// co-located on ONE XCD (runtime election via HW_REG_XCC_ID), exchanging h
// through the shared per-XCD L2 with sc0 loads/stores.
//
// 64 candidate WGs; pigeonhole guarantees some XCD receives >= 8; first XCD
// whose 8th WG arrives claims the job. Non-elected WGs exit. A one-time sc0
// token handshake (sc0-only cache lines) validates same-XCD L2 coherence;
// the verdict is agreed by ALL workers via a two-phase AND+count protocol on
// agent-scope atomics (atomic-only cache lines), so every worker uses the
// SAME mode -- mixed sc0/agent exchange (round-3 bug) cannot occur. On any
// validation failure all workers fall back to agent-scope atomics (proven
// round-2 path: correct, ~15 ms).
//
// Worker g owns rows [64g, 64g+64). Wave w owns columns [64w, 64w+64);
// each lane holds 64 W_hh fp32 in VGPRs (pinned via empty asm). Finalize is
// distributed: wave w reduces rows [8w,8w+8) via shfl_xor and applies tanh.
// ---------------------------------------------------------------------------
__global__ __launch_bounds__(512, 2) void rnn_rec(const float* __restrict__ XPA,
                                                  const float* __restrict__ XPB,
                                                  float* HA, float* HB,
                                                  const float* __restrict__ Whh,
                                                  int* ctl) {
    __shared__ int role_sh, mode_sh;
    const int tid = threadIdx.x;

    if (tid == 0) {
        unsigned xcc;
        asm volatile("s_getreg_b32 %0, hwreg(20, 0, 32)" : "=s"(xcc));  // HW_REG_XCC_ID
        xcc &= 7u;
        int idx = __hip_atomic_fetch_add(&ctl[xcc], 1, __ATOMIC_RELAXED,
                                         __HIP_MEMORY_SCOPE_AGENT);
        int role = -1, mode = 0;
        if (idx < 8) {
            if (idx == 7) {  // 8th arrival on this XCD: try to elect it
                int exp = -1;
                __hip_atomic_compare_exchange_strong(&ctl[8], &exp, (int)xcc,
                    __ATOMIC_RELAXED, __ATOMIC_RELAXED, __HIP_MEMORY_SCOPE_AGENT);
            }
            int e = -1, sp = 0;
            do {
                e = __hip_atomic_load(&ctl[8], __ATOMIC_RELAXED,
                                      __HIP_MEMORY_SCOPE_AGENT);
            } while (e < 0 && ++sp < 1000000);
            if (e == (int)xcc) {
                role = idx;
                // --- phase 1: sc0 token handshake (sc0-only lines) ---
                unsigned* tok = (unsigned*)&ctl[64];
                store_u32_sc0(&tok[role], MAGIC);
                int ok = 1;
                for (int j = 0; j < 8; ++j) {
                    unsigned v; int sp2 = 0;
                    do { v = load_u32_sc0(&tok[j]); }
                    while (v != MAGIC && ++sp2 < SPIN_CAP);
                    ok &= (v == MAGIC);
                }
                // --- phase 2: unanimous mode agreement (agent-only lines) ---
                __hip_atomic_fetch_and(&ctl[10], ok, __ATOMIC_ACQ_REL,
                                       __HIP_MEMORY_SCOPE_AGENT);
                __hip_atomic_fetch_add(&ctl[9], 1, __ATOMIC_ACQ_REL,
                                       __HIP_MEMORY_SCOPE_AGENT);
                int c, sp3 = 0;
                do {
                    c = __hip_atomic_load(&ctl[9], __ATOMIC_ACQUIRE,
                                          __HIP_MEMORY_SCOPE_AGENT);
                } while (c < 8 && ++sp3 < 50000000);
                if (c >= 8) {
                    mode = (__hip_atomic_load(&ctl[10], __ATOMIC_ACQUIRE,
                                              __HIP_MEMORY_SCOPE_AGENT) == 1);
                } else {
                    mode = 0;   // unreachable in practice
                }
            }
        }
        role_sh = role;
        mode_sh = mode;
    }
    __syncthreads();
    const int g = role_sh;
    if (g < 0) return;           // loiterer: exit, frees the CU
    const int mode = mode_sh;

    const int w   = tid >> 6;          // wave 0..7
    const int l   = tid & 63;          // lane
    const int row = g * 64 + l;        // this lane's output row (for weights)
    const int colbase = w * 64;        // this wave's column block

    __shared__ __align__(16) float hs[8][64];   // per-wave h staging
    __shared__ float P[8][73];                  // partials (padded)
    __shared__ float h_ownA[64];
    __shared__ float h_ownB[64];

    // Load this lane's 64 weights and PIN them in VGPRs (round-2 profile
    // showed VGPR_Count=60 -> compiler was re-loading them in-loop).
    float wr[64];
    {
        const float* wp = Whh + (size_t)row * RNN + colbase;
#pragma unroll
        for (int j4 = 0; j4 < 16; ++j4) {
            float4 v = *(const float4*)(wp + 4 * j4);
            wr[4 * j4 + 0] = v.x;
            wr[4 * j4 + 1] = v.y;
            wr[4 * j4 + 2] = v.z;
            wr[4 * j4 + 3] = v.w;
        }
    }
#pragma unroll
    for (int i = 0; i < 64; ++i) asm volatile("" : "+v"(wr[i]));

    // xp prefetch (lanes 0..7 of each wave own rows 8w..8w+7)
    float xpA_cur = 0.0f, xpB_cur = 0.0f;
    if (l < 8) {
        xpA_cur = XPA[g * 64 + 8 * w + l];
        xpB_cur = XPB[g * 64 + 8 * w + l];
    }

    unsigned* HAu = (unsigned*)HA;
    unsigned* HBu = (unsigned*)HB;

    auto phase = [&](const float* __restrict__ XP, unsigned* Hu, float* h_own,
                     float& xp_cur, int t) {
        // 1) obtain h[t] for my column block
        float hv;
        if (w == g && t > 0) {
            hv = h_own[l];                       // own slice via LDS
        } else {
            unsigned* pp = Hu + (size_t)t * RNN + colbase + l;
            unsigned u;
            int tries = 0;
            if (mode) {
                do { u = load_u32_sc0(pp); }
                while (__any((int)(u == CANARY_BITS)) && ++tries < SPIN_CAP);
            } else {
                do {
                    u = __hip_atomic_load(pp, __ATOMIC_RELAXED,
                                          __HIP_MEMORY_SCOPE_AGENT);
                } while (__any((int)(u == CANARY_BITS)) && ++tries < SPIN_CAP);
            }
            hv = __uint_as_float(u);
        }

        // 2) stage to LDS, broadcast-read, 64 FMAs (rotated loads)
        hs[w][l] = hv;
        __builtin_amdgcn_wave_barrier();
        float a0 = 0.0f, a1 = 0.0f, a2 = 0.0f, a3 = 0.0f;
        float4 h4 = *(const float4*)&hs[w][0];
#pragma unroll
        for (int j4 = 0; j4 < 16; ++j4) {
            float4 cur = h4;
            if (j4 < 15) h4 = *(const float4*)&hs[w][4 * (j4 + 1)];
            a0 = fmaf(wr[4 * j4 + 0], cur.x, a0);
            a1 = fmaf(wr[4 * j4 + 1], cur.y, a1);
            a2 = fmaf(wr[4 * j4 + 2], cur.z, a2);
            a3 = fmaf(wr[4 * j4 + 3], cur.w, a3);
        }
        P[w][l] = (a0 + a1) + (a2 + a3);
        __syncthreads();

        // 3) distributed finalize: wave w reduces rows [8w, 8w+8)
        float v = P[l >> 3][8 * w + (l & 7)];
        v += __shfl_xor(v, 8);
        v += __shfl_xor(v, 16);
        v += __shfl_xor(v, 32);
        if (l < 8) {
            const int r = 8 * w + l;             // row within WG
            float hn = tanhf(v + xp_cur);
            unsigned ub = __float_as_uint(hn);
            unsigned* gp = Hu + (size_t)(t + 1) * RNN + g * 64 + r;
            if (mode) store_u32_sc0(gp, ub);
            else __hip_atomic_store(gp, ub, __ATOMIC_RELAXED,
                                    __HIP_MEMORY_SCOPE_AGENT);
            h_own[r] = hn;
            const int tn = (t + 1 < SEQ) ? (t + 1) : (SEQ - 1);
            xp_cur = XP[(size_t)tn * RNN + g * 64 + r];   // prefetch next step
        }
        __syncthreads();
    };

    for (int t = 0; t < SEQ; ++t) {
        phase(XPA, HAu, h_ownA, xpA_cur, t);   // seq A
        phase(XPB, HBu, h_ownB, xpB_cur, t);   // seq B (hides A's L2 latency)
    }
}

// ---------------------------------------------------------------------------
// K_hid: hid = relu(W_hid @ cat([h1;h2]) + b_hid).
// ---------------------------------------------------------------------------
__global__ __launch_bounds__(1024) void k_hid(const float* HA, const float* HB,
                                              const float* __restrict__ Whid,
                                              const float* __restrict__ bhid,
                                              float* __restrict__ hid) {
    __shared__ float cat[2 * RNN];
    const int tid = threadIdx.x;
    cat[tid] = (tid < RNN) ? HA[(size_t)SEQ * RNN + tid]
                           : HB[(size_t)SEQ * RNN + (tid - RNN)];
    __syncthreads();

    const int rl = tid >> 5;
    const int cl = tid & 31;
    const int r  = blockIdx.x * 32 + rl;
    float acc = 0.0f;
#pragma unroll
    for (int i = 0; i < 32; ++i) {
        const int c = cl + 32 * i;
        acc = fmaf(Whid[(size_t)r * (2 * RNN) + c], cat[c], acc);
    }
    for (int d = 16; d > 0; d >>= 1) acc += __shfl_down(acc, d, 32);
    if (cl == 0) {
        float h = acc + bhid[r];
        hid[r] = (h > 0.0f) ? h : 0.0f;
    }
}

// ---------------------------------------------------------------------------
// K_out: out = sigmoid(W_out . hid + b_out)
// ---------------------------------------------------------------------------
__global__ __launch_bounds__(1024) void k_out(const float* __restrict__ hid,
                                              const float* __restrict__ Wout,
                                              const float* __restrict__ bout,
                                              float* __restrict__ out) {
    const int tid = threadIdx.x;
    float v = hid[tid] * Wout[tid];
    for (int d = 32; d > 0; d >>= 1) v += __shfl_down(v, d, 64);
    __shared__ float red[16];
    if ((tid & 63) == 0) red[tid >> 6] = v;
    __syncthreads();
    if (tid < 16) {
        float s = red[tid];
        for (int d = 8; d > 0; d >>= 1) s += __shfl_down(s, d, 16);
        if (tid == 0) out[0] = 1.0f / (1.0f + expf(-(s + bout[0])));
    }
}

// ---------------------------------------------------------------------------
// kernel_launch
// ---------------------------------------------------------------------------
extern "C" void kernel_launch(void* const* d_in, const int* in_sizes, int n_in,
                              void* d_out, int out_size, void* d_ws, size_t ws_size,
                              hipStream_t stream) {
    const void*  s1   = d_in[0];
    const void*  s2   = d_in[1];
    const float* emb  = (const float*)d_in[2];
    const float* Wih  = (const float*)d_in[3];
    const float* Whh  = (const float*)d_in[4];
    const float* Whid = (const float*)d_in[5];
    const float* bhid = (const float*)d_in[6];
    const float* Wout = (const float*)d_in[7];
    const float* bout = (const float*)d_in[8];
    float* out = (float*)d_out;

    // Workspace layout: ctl (512B, line-isolated coherence domains) first,
    // then fp32 arrays: XP_A | XP_B | H_A | H_B | hid | flag
    int* ctl = (int*)d_ws;
    float* XPA  = (float*)((char*)d_ws + CTL_INTS * sizeof(int));
    float* XPB  = XPA + (size_t)SEQ * RNN;
    float* HA   = XPB + (size_t)SEQ * RNN;
    float* HB   = HA + (size_t)(SEQ + 1) * RNN;
    float* hid  = HB + (size_t)(SEQ + 1) * RNN;
    unsigned int* flag = (unsigned int*)(hid + HID);

    k_detect<<<1, 256, 0, stream>>>((const unsigned int*)s1,
                                    (const unsigned int*)s2, flag);
    k_init<<<512, 256, 0, stream>>>(HA, HB, ctl);
    k_xp<<<SEQ / 64, 512, 0, stream>>>(s1, emb, Wih, XPA, flag);
    k_xp<<<SEQ / 64, 512, 0, stream>>>(s2, emb, Wih, XPB, flag);
    // 64 candidates, 8 same-XCD workers survive the election.
    rnn_rec<<<64, 512, 0, stream>>>(XPA, XPB, HA, HB, Whh, ctl);
    k_hid<<<HID / 32, 1024, 0, stream>>>(HA, HB, Whid, bhid, hid);
    k_out<<<1, 1024, 0, stream>>>(hid, Wout, bout, out);
}